// Round 2
// baseline (510.162 us; speedup 1.0000x reference)
//
#include <hip/hip_runtime.h>

#define G 16
#define N 128
#define FI 18432
#define SLABS 16
#define KS (FI / SLABS)
#define KT 32
#define NTILES (KS / KT)
#define EPSV 1e-5f

// Pass 1: per-(group, k-slab) partial C = Z Z^T (128x128) + partial row sums.
__global__ __launch_bounds__(256) void k_syrk(const float* __restrict__ Wt,
                                              float* __restrict__ partC,
                                              float* __restrict__ partRS) {
  const int slab = blockIdx.x, g = blockIdx.y;
  const int t = threadIdx.x;
  const int ty = t >> 4, tx = t & 15;
  __shared__ float As[KT][132];
  const float* base = Wt + (size_t)g * N * FI + (size_t)slab * KS;

  float acc[8][8];
#pragma unroll
  for (int i = 0; i < 8; ++i)
#pragma unroll
    for (int j = 0; j < 8; ++j) acc[i][j] = 0.f;
  float rs = 0.f;

  float4 stage[4];
#pragma unroll
  for (int j = 0; j < 4; ++j) {
    int f = j * 256 + t; int row = f >> 3, c4 = f & 7;
    stage[j] = *(const float4*)(base + (size_t)row * FI + c4 * 4);
  }

  for (int tile = 0; tile < NTILES; ++tile) {
    __syncthreads();
#pragma unroll
    for (int j = 0; j < 4; ++j) {
      int f = j * 256 + t; int row = f >> 3, c4 = f & 7;
      float4 v = stage[j];
      As[c4 * 4 + 0][row] = v.x; As[c4 * 4 + 1][row] = v.y;
      As[c4 * 4 + 2][row] = v.z; As[c4 * 4 + 3][row] = v.w;
    }
    __syncthreads();
    if (tile + 1 < NTILES) {
      const float* nb = base + (size_t)(tile + 1) * KT;
#pragma unroll
      for (int j = 0; j < 4; ++j) {
        int f = j * 256 + t; int row = f >> 3, c4 = f & 7;
        stage[j] = *(const float4*)(nb + (size_t)row * FI + c4 * 4);
      }
    }
    if (t < N) {
#pragma unroll
      for (int k = 0; k < KT; ++k) rs += As[k][t];
    }
    for (int k = 0; k < KT; ++k) {
      float4 a0 = *(const float4*)&As[k][ty * 8];
      float4 a1 = *(const float4*)&As[k][ty * 8 + 4];
      float4 b0 = *(const float4*)&As[k][tx * 4];
      float4 b1 = *(const float4*)&As[k][64 + tx * 4];
      float ar[8] = {a0.x, a0.y, a0.z, a0.w, a1.x, a1.y, a1.z, a1.w};
      float br[8] = {b0.x, b0.y, b0.z, b0.w, b1.x, b1.y, b1.z, b1.w};
#pragma unroll
      for (int i = 0; i < 8; ++i)
#pragma unroll
        for (int j = 0; j < 8; ++j) acc[i][j] += ar[i] * br[j];
    }
  }

  float* outp = partC + ((size_t)(g * SLABS + slab) << 14);
#pragma unroll
  for (int i = 0; i < 8; ++i) {
    int r = ty * 8 + i;
    *(float4*)(outp + r * N + tx * 4) =
        make_float4(acc[i][0], acc[i][1], acc[i][2], acc[i][3]);
    *(float4*)(outp + r * N + 64 + tx * 4) =
        make_float4(acc[i][4], acc[i][5], acc[i][6], acc[i][7]);
  }
  if (t < N) partRS[(g * SLABS + slab) * N + t] = rs;
}

// Pass 2: reduce slab partials -> S (unnormalized, mean-corrected, +eps I),
// row means, Frobenius-norm^2 accumulator.
__global__ __launch_bounds__(256) void k_reduce(const float* __restrict__ partC,
                                                const float* __restrict__ partRS,
                                                float* __restrict__ m_vec,
                                                float* __restrict__ S_un,
                                                float* __restrict__ normacc) {
  const int chunk = blockIdx.x;
  const int g = blockIdx.y;
  const int t = threadIdx.x;
  __shared__ float ms[N];
  if (t < N) {
    float s = 0.f;
    for (int sl = 0; sl < SLABS; ++sl) s += partRS[(g * SLABS + sl) * N + t];
    float mv = s * (1.f / (float)FI);
    ms[t] = mv;
    if (chunk == 0) m_vec[g * N + t] = mv;
  }
  __syncthreads();
  float ssq = 0.f;
#pragma unroll
  for (int i = 0; i < 8; ++i) {
    int e = chunk * 2048 + i * 256 + t;
    int row = e >> 7, col = e & 127;
    float v = 0.f;
    for (int sl = 0; sl < SLABS; ++sl)
      v += partC[((size_t)(g * SLABS + sl) << 14) + e];
    v -= (float)FI * ms[row] * ms[col];
    if (row == col) v += EPSV;
    S_un[((size_t)g << 14) + e] = v;
    ssq += v * v;
  }
  for (int off = 32; off; off >>= 1) ssq += __shfl_down(ssq, off, 64);
  __shared__ float red[4];
  if ((t & 63) == 0) red[t >> 6] = ssq;
  __syncthreads();
  if (t == 0) atomicAdd(normacc + g, red[0] + red[1] + red[2] + red[3]);
}

// S_n = S/||S||_F ; B1 = 1.5 I - 0.5 S_n (fused NS iteration 1); output scale.
__global__ __launch_bounds__(256) void k_nsinit(const float* __restrict__ S_un,
                                                const float* __restrict__ normacc,
                                                float* __restrict__ S_n,
                                                float* __restrict__ Bm,
                                                float* __restrict__ scaleg) {
  const int chunk = blockIdx.x, g = blockIdx.y;
  const int t = threadIdx.x;
  float norm = sqrtf(normacc[g]);
  float inv = 1.f / norm;
  if (chunk == 0 && t == 0) scaleg[g] = 1.f / sqrtf(norm);
#pragma unroll
  for (int i = 0; i < 8; ++i) {
    int e = chunk * 2048 + i * 256 + t;
    int row = e >> 7, col = e & 127;
    float s = S_un[((size_t)g << 14) + e] * inv;
    S_n[((size_t)g << 14) + e] = s;
    Bm[((size_t)g << 14) + e] = (row == col ? 1.5f : 0.f) - 0.5f * s;
  }
}

// NS step A: T1 = B@B and T2 = B@S_n (blockIdx.y selects which product).
__global__ __launch_bounds__(256) void k_nsmm2(const float* __restrict__ Bm,
                                               const float* __restrict__ S_n,
                                               float* __restrict__ T1,
                                               float* __restrict__ T2) {
  const int rb = blockIdx.x, which = blockIdx.y, g = blockIdx.z;
  const int t = threadIdx.x;
  const int r = t >> 4, c0 = (t & 15) * 4;
  const float* A = Bm + ((size_t)g << 14) + rb * 16 * N;
  const float* R = which ? (S_n + ((size_t)g << 14)) : (Bm + ((size_t)g << 14));
  float* outp = (which ? T2 : T1) + ((size_t)g << 14) + rb * 16 * N;
  __shared__ float Rs[N][132];
  __shared__ float As2[16][132];
#pragma unroll
  for (int j = 0; j < 16; ++j) {
    int f = j * 256 + t; int row = f >> 5, c4 = f & 31;
    *(float4*)&Rs[row][c4 * 4] = *(const float4*)(R + row * N + c4 * 4);
  }
#pragma unroll
  for (int j = 0; j < 2; ++j) {
    int f = j * 256 + t; int row = f >> 5, c4 = f & 31;
    *(float4*)&As2[row][c4 * 4] = *(const float4*)(A + row * N + c4 * 4);
  }
  __syncthreads();
  float acc[8];
#pragma unroll
  for (int j = 0; j < 8; ++j) acc[j] = 0.f;
  for (int k = 0; k < N; ++k) {
    float a = As2[r][k];
    float4 b0 = *(const float4*)&Rs[k][c0];
    float4 b1 = *(const float4*)&Rs[k][64 + c0];
    acc[0] += a * b0.x; acc[1] += a * b0.y; acc[2] += a * b0.z; acc[3] += a * b0.w;
    acc[4] += a * b1.x; acc[5] += a * b1.y; acc[6] += a * b1.z; acc[7] += a * b1.w;
  }
  *(float4*)(outp + r * N + c0) = make_float4(acc[0], acc[1], acc[2], acc[3]);
  *(float4*)(outp + r * N + 64 + c0) = make_float4(acc[4], acc[5], acc[6], acc[7]);
}

// NS step B: B = 1.5 B - 0.5 * T1@T2.
__global__ __launch_bounds__(256) void k_nsupd(const float* __restrict__ T1,
                                               const float* __restrict__ T2,
                                               float* __restrict__ Bm) {
  const int rb = blockIdx.x, g = blockIdx.y;
  const int t = threadIdx.x;
  const int r = t >> 4, c0 = (t & 15) * 4;
  const float* A = T1 + ((size_t)g << 14) + rb * 16 * N;
  const float* R = T2 + ((size_t)g << 14);
  float* Bp = Bm + ((size_t)g << 14) + rb * 16 * N;
  __shared__ float Rs[N][132];
  __shared__ float As2[16][132];
#pragma unroll
  for (int j = 0; j < 16; ++j) {
    int f = j * 256 + t; int row = f >> 5, c4 = f & 31;
    *(float4*)&Rs[row][c4 * 4] = *(const float4*)(R + row * N + c4 * 4);
  }
#pragma unroll
  for (int j = 0; j < 2; ++j) {
    int f = j * 256 + t; int row = f >> 5, c4 = f & 31;
    *(float4*)&As2[row][c4 * 4] = *(const float4*)(A + row * N + c4 * 4);
  }
  __syncthreads();
  float acc[8];
#pragma unroll
  for (int j = 0; j < 8; ++j) acc[j] = 0.f;
  for (int k = 0; k < N; ++k) {
    float a = As2[r][k];
    float4 b0 = *(const float4*)&Rs[k][c0];
    float4 b1 = *(const float4*)&Rs[k][64 + c0];
    acc[0] += a * b0.x; acc[1] += a * b0.y; acc[2] += a * b0.z; acc[3] += a * b0.w;
    acc[4] += a * b1.x; acc[5] += a * b1.y; acc[6] += a * b1.z; acc[7] += a * b1.w;
  }
  float4 bo0 = *(const float4*)(Bp + r * N + c0);
  float4 bo1 = *(const float4*)(Bp + r * N + 64 + c0);
  *(float4*)(Bp + r * N + c0) =
      make_float4(1.5f * bo0.x - 0.5f * acc[0], 1.5f * bo0.y - 0.5f * acc[1],
                  1.5f * bo0.z - 0.5f * acc[2], 1.5f * bo0.w - 0.5f * acc[3]);
  *(float4*)(Bp + r * N + 64 + c0) =
      make_float4(1.5f * bo1.x - 0.5f * acc[4], 1.5f * bo1.y - 0.5f * acc[5],
                  1.5f * bo1.z - 0.5f * acc[6], 1.5f * bo1.w - 0.5f * acc[7]);
}

// Final: W = (B @ Z - (B m) 1^T) * rsqrt(||S||_F).
#define CT 128
__global__ __launch_bounds__(256) void k_final(const float* __restrict__ Wt,
                                               const float* __restrict__ Bm,
                                               const float* __restrict__ m_vec,
                                               const float* __restrict__ scaleg,
                                               float* __restrict__ outp) {
  const int ct = blockIdx.x;
  const int rh = blockIdx.y;
  const int g = blockIdx.z;
  const int t = threadIdx.x;
  const int ty = t >> 4, tx = t & 15;
  __shared__ float Bs[64][132];
  __shared__ float Zs[KT][132];
  __shared__ float cs[64];
  __shared__ float msh[N];

  const float* Bbase = Bm + ((size_t)g << 14) + rh * 64 * N;
#pragma unroll
  for (int j = 0; j < 8; ++j) {
    int f = j * 256 + t; int row = f >> 5, c4 = f & 31;
    *(float4*)&Bs[row][c4 * 4] = *(const float4*)(Bbase + row * N + c4 * 4);
  }
  if (t < N) msh[t] = m_vec[g * N + t];
  __syncthreads();
  if (t < 64) {
    float c = 0.f;
    for (int k = 0; k < N; ++k) c += Bs[t][k] * msh[k];
    cs[t] = c;
  }

  float acc[4][8];
#pragma unroll
  for (int i = 0; i < 4; ++i)
#pragma unroll
    for (int j = 0; j < 8; ++j) acc[i][j] = 0.f;

  const float* zbase = Wt + (size_t)g * N * FI + (size_t)ct * CT;
  for (int kc = 0; kc < 4; ++kc) {
    __syncthreads();
#pragma unroll
    for (int j = 0; j < 4; ++j) {
      int f = j * 256 + t; int kr = f >> 5, c4 = f & 31;
      *(float4*)&Zs[kr][c4 * 4] =
          *(const float4*)(zbase + (size_t)(kc * KT + kr) * FI + c4 * 4);
    }
    __syncthreads();
#pragma unroll
    for (int kb = 0; kb < 8; ++kb) {
      float br[4][4];
#pragma unroll
      for (int i = 0; i < 4; ++i)
        *(float4*)br[i] = *(const float4*)&Bs[ty * 4 + i][kc * KT + kb * 4];
#pragma unroll
      for (int kk = 0; kk < 4; ++kk) {
        float4 z0 = *(const float4*)&Zs[kb * 4 + kk][tx * 4];
        float4 z1 = *(const float4*)&Zs[kb * 4 + kk][64 + tx * 4];
        float zr[8] = {z0.x, z0.y, z0.z, z0.w, z1.x, z1.y, z1.z, z1.w};
#pragma unroll
        for (int i = 0; i < 4; ++i)
#pragma unroll
          for (int j = 0; j < 8; ++j) acc[i][j] += br[i][kk] * zr[j];
      }
    }
  }

  const float scl = scaleg[g];
  size_t obase = ((size_t)(g * N + rh * 64)) * FI + (size_t)ct * CT;
#pragma unroll
  for (int i = 0; i < 4; ++i) {
    int r = ty * 4 + i;
    float cc = cs[r];
    *(float4*)(outp + obase + (size_t)r * FI + tx * 4) =
        make_float4((acc[i][0] - cc) * scl, (acc[i][1] - cc) * scl,
                    (acc[i][2] - cc) * scl, (acc[i][3] - cc) * scl);
    *(float4*)(outp + obase + (size_t)r * FI + 64 + tx * 4) =
        make_float4((acc[i][4] - cc) * scl, (acc[i][5] - cc) * scl,
                    (acc[i][6] - cc) * scl, (acc[i][7] - cc) * scl);
  }
}

extern "C" void kernel_launch(void* const* d_in, const int* in_sizes, int n_in,
                              void* d_out, int out_size, void* d_ws, size_t ws_size,
                              hipStream_t stream) {
  (void)in_sizes; (void)n_in; (void)out_size; (void)ws_size;
  const float* Wt = (const float*)d_in[0];
  float* outp = (float*)d_out;

  float* ws = (float*)d_ws;
  float* partC = ws;                 // [G][SLABS][128][128]  16 MB
  float* partRS = partC + 4194304;   // [G][SLABS][128]
  float* m_vec = partRS + 32768;     // [G][128]
  float* S_un = m_vec + 2048;        // [G][128][128]
  float* S_n = S_un + 262144;
  float* Bm = S_n + 262144;
  float* T1 = Bm + 262144;
  float* T2 = T1 + 262144;
  float* normacc = T2 + 262144;      // [G]
  float* scaleg = normacc + 16;      // [G]

  hipMemsetAsync(normacc, 0, G * sizeof(float), stream);
  k_syrk<<<dim3(SLABS, G), 256, 0, stream>>>(Wt, partC, partRS);
  k_reduce<<<dim3(8, G), 256, 0, stream>>>(partC, partRS, m_vec, S_un, normacc);
  k_nsinit<<<dim3(8, G), 256, 0, stream>>>(S_un, normacc, S_n, Bm, scaleg);
  for (int it = 0; it < 4; ++it) {
    k_nsmm2<<<dim3(8, 2, G), 256, 0, stream>>>(Bm, S_n, T1, T2);
    k_nsupd<<<dim3(8, G), 256, 0, stream>>>(T1, T2, Bm);
  }
  k_final<<<dim3(FI / CT, 2, G), 256, 0, stream>>>(Wt, Bm, m_vec, scaleg, outp);
}

// Round 5
// 426.181 us; speedup vs baseline: 1.1971x; 1.1971x over previous
//
#include <hip/hip_runtime.h>

#define G 16
#define N 128
#define FI 18432
#define EPSV 1e-5f

typedef __attribute__((ext_vector_type(8))) short short8;
typedef __attribute__((ext_vector_type(4))) float f32x4;

__device__ inline unsigned short bf16_rn(float x) {
  unsigned u = __float_as_uint(x);
  u += 0x7FFFu + ((u >> 16) & 1u);
  return (unsigned short)(u >> 16);
}
__device__ inline float bf16f(unsigned short h) {
  return __uint_as_float(((unsigned)h) << 16);
}
__device__ inline void split2(float x, unsigned short& h, unsigned short& l) {
  h = bf16_rn(x);
  l = bf16_rn(x - bf16f(h));
}
__device__ inline f32x4 zero4() {
  f32x4 z = {0.f, 0.f, 0.f, 0.f};
  return z;
}

// ---------------------------------------------------------------------------
// Pass 1 (MFMA): per-(group,slab) partial C = Z Z^T via bf16 hi/lo 4-product
// split, plus partial row sums. 256 thr = 4 waves; wave w owns rows 32w..32w+31
// as 2x8 tiles of 16x16 (mfma_f32_16x16x32_bf16). Z chunk (128x64 fp32) staged
// in LDS as bf16 hi/lo, stride 72 shorts (16B-aligned, 2-way-free bank layout).
// ---------------------------------------------------------------------------
template <int SLABS>
__global__ __launch_bounds__(256, 2) void k_syrk(const float* __restrict__ Wt,
                                                 float* __restrict__ partC,
                                                 float* __restrict__ partRS) {
  constexpr int KS = FI / SLABS;
  constexpr int NCH = KS / 64;
  const int slab = blockIdx.x, g = blockIdx.y;
  const int t = threadIdx.x;
  const int w = t >> 6, lane = t & 63;
  __shared__ __align__(16) unsigned short Hs[128][72];
  __shared__ __align__(16) unsigned short Ls[128][72];

  const float* base = Wt + (size_t)g * N * FI + (size_t)slab * KS;

  f32x4 acc[2][8];
#pragma unroll
  for (int i = 0; i < 2; ++i)
#pragma unroll
    for (int j = 0; j < 8; ++j) acc[i][j] = zero4();
  float rs[8];
#pragma unroll
  for (int j = 0; j < 8; ++j) rs[j] = 0.f;

  for (int ch = 0; ch < NCH; ++ch) {
    float4 v[8];
#pragma unroll
    for (int j = 0; j < 8; ++j) {
      int f = t + 256 * j;
      int row = f >> 4, c4 = f & 15;
      v[j] = *(const float4*)(base + (size_t)row * FI + ch * 64 + c4 * 4);
    }
    __syncthreads();  // prior MFMA reads of LDS done
#pragma unroll
    for (int j = 0; j < 8; ++j) {
      int f = t + 256 * j;
      int row = f >> 4, c4 = f & 15;
      rs[j] += v[j].x + v[j].y + v[j].z + v[j].w;
      unsigned short h0, h1, h2, h3, l0, l1, l2, l3;
      split2(v[j].x, h0, l0);
      split2(v[j].y, h1, l1);
      split2(v[j].z, h2, l2);
      split2(v[j].w, h3, l3);
      *(uint2*)&Hs[row][c4 * 4] =
          make_uint2((unsigned)h0 | ((unsigned)h1 << 16),
                     (unsigned)h2 | ((unsigned)h3 << 16));
      *(uint2*)&Ls[row][c4 * 4] =
          make_uint2((unsigned)l0 | ((unsigned)l1 << 16),
                     (unsigned)l2 | ((unsigned)l3 << 16));
    }
    __syncthreads();
#pragma unroll
    for (int kk = 0; kk < 2; ++kk) {  // two K=32 steps per 64-col chunk
      const int kof = kk * 32 + (lane >> 4) * 8;
      short8 ah[2], al[2];
#pragma unroll
      for (int i = 0; i < 2; ++i) {
        int r = (2 * w + i) * 16 + (lane & 15);
        ah[i] = *(const short8*)&Hs[r][kof];
        al[i] = *(const short8*)&Ls[r][kof];
      }
#pragma unroll
      for (int jb = 0; jb < 8; ++jb) {
        int r = jb * 16 + (lane & 15);
        short8 zh = *(const short8*)&Hs[r][kof];
        short8 zl = *(const short8*)&Ls[r][kof];
#pragma unroll
        for (int i = 0; i < 2; ++i) {
          acc[i][jb] = __builtin_amdgcn_mfma_f32_16x16x32_bf16(ah[i], zh, acc[i][jb], 0, 0, 0);
          acc[i][jb] = __builtin_amdgcn_mfma_f32_16x16x32_bf16(ah[i], zl, acc[i][jb], 0, 0, 0);
          acc[i][jb] = __builtin_amdgcn_mfma_f32_16x16x32_bf16(al[i], zh, acc[i][jb], 0, 0, 0);
          acc[i][jb] = __builtin_amdgcn_mfma_f32_16x16x32_bf16(al[i], zl, acc[i][jb], 0, 0, 0);
        }
      }
    }
  }

  float* outp = partC + ((size_t)(g * SLABS + slab) << 14);
#pragma unroll
  for (int i = 0; i < 2; ++i)
#pragma unroll
    for (int jb = 0; jb < 8; ++jb)
#pragma unroll
      for (int r = 0; r < 4; ++r) {
        int row = (2 * w + i) * 16 + (lane >> 4) * 4 + r;
        int col = jb * 16 + (lane & 15);
        outp[row * N + col] = acc[i][jb][r];
      }
#pragma unroll
  for (int j = 0; j < 8; ++j) {
    float s = rs[j];
    s += __shfl_down(s, 8, 16);
    s += __shfl_down(s, 4, 16);
    s += __shfl_down(s, 2, 16);
    s += __shfl_down(s, 1, 16);
    if ((t & 15) == 0) {
      int row = (t >> 4) + 16 * j;
      partRS[(size_t)(g * SLABS + slab) * N + row] = s;
    }
  }
}

// ---------------------------------------------------------------------------
// Pass 2: reduce slab partials -> S (mean-corrected, +eps I), row means,
// Frobenius norm^2. Grid (16, G) = 256 blocks.
// ---------------------------------------------------------------------------
template <int SLABS>
__global__ __launch_bounds__(256) void k_reduce(const float* __restrict__ partC,
                                                const float* __restrict__ partRS,
                                                float* __restrict__ m_vec,
                                                float* __restrict__ S_un,
                                                float* __restrict__ normacc) {
  const int chunk = blockIdx.x;
  const int g = blockIdx.y;
  const int t = threadIdx.x;
  __shared__ float ms[N];
  if (t < N) {
    float s = 0.f;
    for (int sl = 0; sl < SLABS; ++sl) s += partRS[(size_t)(g * SLABS + sl) * N + t];
    float mv = s * (1.f / (float)FI);
    ms[t] = mv;
    if (chunk == 0) m_vec[g * N + t] = mv;
  }
  __syncthreads();
  float ssq = 0.f;
#pragma unroll
  for (int i = 0; i < 4; ++i) {
    int e = chunk * 1024 + i * 256 + t;
    int row = e >> 7, col = e & 127;
    float v = 0.f;
    for (int sl = 0; sl < SLABS; ++sl)
      v += partC[((size_t)(g * SLABS + sl) << 14) + e];
    v -= (float)FI * ms[row] * ms[col];
    if (row == col) v += EPSV;
    S_un[((size_t)g << 14) + e] = v;
    ssq += v * v;
  }
  for (int off = 32; off; off >>= 1) ssq += __shfl_down(ssq, off, 64);
  __shared__ float red[4];
  if ((t & 63) == 0) red[t >> 6] = ssq;
  __syncthreads();
  if (t == 0) atomicAdd(normacc + g, red[0] + red[1] + red[2] + red[3]);
}

// S_n = S/||S||_F ; B1 = 1.5 I - 0.5 S_n ; output scale.
__global__ __launch_bounds__(256) void k_nsinit(const float* __restrict__ S_un,
                                                const float* __restrict__ normacc,
                                                float* __restrict__ S_n,
                                                float* __restrict__ Bm,
                                                float* __restrict__ scaleg) {
  const int chunk = blockIdx.x, g = blockIdx.y;
  const int t = threadIdx.x;
  float norm = sqrtf(normacc[g]);
  float inv = 1.f / norm;
  if (chunk == 0 && t == 0) scaleg[g] = 1.f / sqrtf(norm);
#pragma unroll
  for (int i = 0; i < 8; ++i) {
    int e = chunk * 2048 + i * 256 + t;
    int row = e >> 7, col = e & 127;
    float s = S_un[((size_t)g << 14) + e] * inv;
    S_n[((size_t)g << 14) + e] = s;
    Bm[((size_t)g << 14) + e] = (row == col ? 1.5f : 0.f) - 0.5f * s;
  }
}

// NS step A: T1 = B@B and T2 = B@S_n.
__global__ __launch_bounds__(256) void k_nsmm2(const float* __restrict__ Bm,
                                               const float* __restrict__ S_n,
                                               float* __restrict__ T1,
                                               float* __restrict__ T2) {
  const int rb = blockIdx.x, which = blockIdx.y, g = blockIdx.z;
  const int t = threadIdx.x;
  const int r = t >> 4, c0 = (t & 15) * 4;
  const float* A = Bm + ((size_t)g << 14) + rb * 16 * N;
  const float* R = which ? (S_n + ((size_t)g << 14)) : (Bm + ((size_t)g << 14));
  float* outp = (which ? T2 : T1) + ((size_t)g << 14) + rb * 16 * N;
  __shared__ float Rs[N][132];
  __shared__ float As2[16][132];
#pragma unroll
  for (int j = 0; j < 16; ++j) {
    int f = j * 256 + t; int row = f >> 5, c4 = f & 31;
    *(float4*)&Rs[row][c4 * 4] = *(const float4*)(R + row * N + c4 * 4);
  }
#pragma unroll
  for (int j = 0; j < 2; ++j) {
    int f = j * 256 + t; int row = f >> 5, c4 = f & 31;
    *(float4*)&As2[row][c4 * 4] = *(const float4*)(A + row * N + c4 * 4);
  }
  __syncthreads();
  float acc[8];
#pragma unroll
  for (int j = 0; j < 8; ++j) acc[j] = 0.f;
  for (int k = 0; k < N; ++k) {
    float a = As2[r][k];
    float4 b0 = *(const float4*)&Rs[k][c0];
    float4 b1 = *(const float4*)&Rs[k][64 + c0];
    acc[0] += a * b0.x; acc[1] += a * b0.y; acc[2] += a * b0.z; acc[3] += a * b0.w;
    acc[4] += a * b1.x; acc[5] += a * b1.y; acc[6] += a * b1.z; acc[7] += a * b1.w;
  }
  *(float4*)(outp + r * N + c0) = make_float4(acc[0], acc[1], acc[2], acc[3]);
  *(float4*)(outp + r * N + 64 + c0) = make_float4(acc[4], acc[5], acc[6], acc[7]);
}

// NS step B: B = 1.5 B - 0.5 * T1@T2.
__global__ __launch_bounds__(256) void k_nsupd(const float* __restrict__ T1,
                                               const float* __restrict__ T2,
                                               float* __restrict__ Bm) {
  const int rb = blockIdx.x, g = blockIdx.y;
  const int t = threadIdx.x;
  const int r = t >> 4, c0 = (t & 15) * 4;
  const float* A = T1 + ((size_t)g << 14) + rb * 16 * N;
  const float* R = T2 + ((size_t)g << 14);
  float* Bp = Bm + ((size_t)g << 14) + rb * 16 * N;
  __shared__ float Rs[N][132];
  __shared__ float As2[16][132];
#pragma unroll
  for (int j = 0; j < 16; ++j) {
    int f = j * 256 + t; int row = f >> 5, c4 = f & 31;
    *(float4*)&Rs[row][c4 * 4] = *(const float4*)(R + row * N + c4 * 4);
  }
#pragma unroll
  for (int j = 0; j < 2; ++j) {
    int f = j * 256 + t; int row = f >> 5, c4 = f & 31;
    *(float4*)&As2[row][c4 * 4] = *(const float4*)(A + row * N + c4 * 4);
  }
  __syncthreads();
  float acc[8];
#pragma unroll
  for (int j = 0; j < 8; ++j) acc[j] = 0.f;
  for (int k = 0; k < N; ++k) {
    float a = As2[r][k];
    float4 b0 = *(const float4*)&Rs[k][c0];
    float4 b1 = *(const float4*)&Rs[k][64 + c0];
    acc[0] += a * b0.x; acc[1] += a * b0.y; acc[2] += a * b0.z; acc[3] += a * b0.w;
    acc[4] += a * b1.x; acc[5] += a * b1.y; acc[6] += a * b1.z; acc[7] += a * b1.w;
  }
  float4 bo0 = *(const float4*)(Bp + r * N + c0);
  float4 bo1 = *(const float4*)(Bp + r * N + 64 + c0);
  *(float4*)(Bp + r * N + c0) =
      make_float4(1.5f * bo0.x - 0.5f * acc[0], 1.5f * bo0.y - 0.5f * acc[1],
                  1.5f * bo0.z - 0.5f * acc[2], 1.5f * bo0.w - 0.5f * acc[3]);
  *(float4*)(Bp + r * N + 64 + c0) =
      make_float4(1.5f * bo1.x - 0.5f * acc[4], 1.5f * bo1.y - 0.5f * acc[5],
                  1.5f * bo1.z - 0.5f * acc[6], 1.5f * bo1.w - 0.5f * acc[7]);
}

// ---------------------------------------------------------------------------
// Final (MFMA): W = (B @ Z - (B m) 1^T) * rsqrt(||S||_F).
// Grid (FI/128, G). B-frags (bf16 hi/lo) held in registers; Z chunk staged
// transposed+packed into LDS (stride 136 shorts, 16B XOR swizzle on k).
// ---------------------------------------------------------------------------
__global__ __launch_bounds__(256, 2) void k_final(const float* __restrict__ Wt,
                                                  const float* __restrict__ Bm,
                                                  const float* __restrict__ m_vec,
                                                  const float* __restrict__ scaleg,
                                                  float* __restrict__ outp) {
  const int ct = blockIdx.x;  // 128-col window
  const int g = blockIdx.y;
  const int t = threadIdx.x;
  const int w = t >> 6, lane = t & 63;
  __shared__ __align__(16) unsigned short Zh[64][136];
  __shared__ __align__(16) unsigned short Zl[64][136];
  __shared__ float msh[N];

  if (t < N) msh[t] = m_vec[g * N + t];
  __syncthreads();

  // B fragments for rows 32w..32w+31, all K=128 (4 chunks of 32), hi/lo.
  short8 bh[2][4], bl[2][4];
  float cs[2] = {0.f, 0.f};
  const float* Bg = Bm + ((size_t)g << 14);
#pragma unroll
  for (int i = 0; i < 2; ++i) {
    int row = (2 * w + i) * 16 + (lane & 15);
#pragma unroll
    for (int kk = 0; kk < 4; ++kk) {
      int kof = kk * 32 + (lane >> 4) * 8;
      float4 p0 = *(const float4*)(Bg + row * N + kof);
      float4 p1 = *(const float4*)(Bg + row * N + kof + 4);
      unsigned short h[8], l[8];
      split2(p0.x, h[0], l[0]); split2(p0.y, h[1], l[1]);
      split2(p0.z, h[2], l[2]); split2(p0.w, h[3], l[3]);
      split2(p1.x, h[4], l[4]); split2(p1.y, h[5], l[5]);
      split2(p1.z, h[6], l[6]); split2(p1.w, h[7], l[7]);
      bh[i][kk] = (short8){(short)h[0], (short)h[1], (short)h[2], (short)h[3],
                           (short)h[4], (short)h[5], (short)h[6], (short)h[7]};
      bl[i][kk] = (short8){(short)l[0], (short)l[1], (short)l[2], (short)l[3],
                           (short)l[4], (short)l[5], (short)l[6], (short)l[7]};
      cs[i] += p0.x * msh[kof] + p0.y * msh[kof + 1] + p0.z * msh[kof + 2] +
               p0.w * msh[kof + 3] + p1.x * msh[kof + 4] + p1.y * msh[kof + 5] +
               p1.z * msh[kof + 6] + p1.w * msh[kof + 7];
    }
    cs[i] += __shfl_xor(cs[i], 16);
    cs[i] += __shfl_xor(cs[i], 32);
  }
  const float scl = scaleg[g];

  for (int sc = 0; sc < 2; ++sc) {
    const float* zb = Wt + (size_t)g * N * FI + ct * 128 + sc * 64;
    __syncthreads();  // prior MFMA reads of Zh/Zl done
#pragma unroll
    for (int jj = 0; jj < 4; ++jj) {
      int idx = t + 256 * jj;
      int n4 = idx & 15, k2 = idx >> 4;  // k2: 0..63 (pairs of k)
      float4 a = *(const float4*)(zb + (size_t)(2 * k2) * FI + n4 * 4);
      float4 b = *(const float4*)(zb + (size_t)(2 * k2 + 1) * FI + n4 * 4);
      int k2s = k2 ^ ((n4 & 3) << 2);
      float av[4] = {a.x, a.y, a.z, a.w};
      float bv[4] = {b.x, b.y, b.z, b.w};
#pragma unroll
      for (int c = 0; c < 4; ++c) {
        int col = n4 * 4 + c;
        unsigned short h0, l0, h1, l1;
        split2(av[c], h0, l0);
        split2(bv[c], h1, l1);
        *(unsigned*)&Zh[col][2 * k2s] = (unsigned)h0 | ((unsigned)h1 << 16);
        *(unsigned*)&Zl[col][2 * k2s] = (unsigned)l0 | ((unsigned)l1 << 16);
      }
    }
    __syncthreads();
    f32x4 acc[2][4];
#pragma unroll
    for (int i = 0; i < 2; ++i)
#pragma unroll
      for (int jb = 0; jb < 4; ++jb) acc[i][jb] = zero4();
#pragma unroll
    for (int kk = 0; kk < 4; ++kk) {
#pragma unroll
      for (int jb = 0; jb < 4; ++jb) {
        int col = jb * 16 + (lane & 15);
        int k2b = (kk * 16 + (lane >> 4) * 4) ^ (((col >> 2) & 3) << 2);
        short8 zh8 = *(const short8*)&Zh[col][2 * k2b];
        short8 zl8 = *(const short8*)&Zl[col][2 * k2b];
#pragma unroll
        for (int i = 0; i < 2; ++i) {
          acc[i][jb] = __builtin_amdgcn_mfma_f32_16x16x32_bf16(bh[i][kk], zh8, acc[i][jb], 0, 0, 0);
          acc[i][jb] = __builtin_amdgcn_mfma_f32_16x16x32_bf16(bh[i][kk], zl8, acc[i][jb], 0, 0, 0);
          acc[i][jb] = __builtin_amdgcn_mfma_f32_16x16x32_bf16(bl[i][kk], zh8, acc[i][jb], 0, 0, 0);
          acc[i][jb] = __builtin_amdgcn_mfma_f32_16x16x32_bf16(bl[i][kk], zl8, acc[i][jb], 0, 0, 0);
        }
      }
    }
#pragma unroll
    for (int i = 0; i < 2; ++i)
#pragma unroll
      for (int r = 0; r < 4; ++r) {
        int rloc = (lane >> 4) * 4 + r;                   // row within 16-block
        float csr = __shfl(cs[i], rloc, 64);              // holder lane = rloc
        int row = (2 * w + i) * 16 + rloc;                // row within group
#pragma unroll
        for (int jb = 0; jb < 4; ++jb) {
          int col = ct * 128 + sc * 64 + jb * 16 + (lane & 15);
          outp[(size_t)(g * N + row) * FI + col] = (acc[i][jb][r] - csr) * scl;
        }
      }
  }
}

// ---------------------------------------------------------------------------
extern "C" void kernel_launch(void* const* d_in, const int* in_sizes, int n_in,
                              void* d_out, int out_size, void* d_ws, size_t ws_size,
                              hipStream_t stream) {
  (void)in_sizes; (void)n_in; (void)out_size;
  const float* Wt = (const float*)d_in[0];
  float* outp = (float*)d_out;
  float* ws = (float*)d_ws;

  const size_t need32 =
      ((size_t)32 * G * 16384 + (size_t)32 * G * N + G * N + 5 * 262144 + 64) * 4;
  const bool big = ws_size >= need32;
  const int slabs = big ? 32 : 16;

  float* partC = ws;
  float* partRS = partC + (size_t)slabs * G * 16384;
  float* m_vec = partRS + (size_t)slabs * G * N;
  float* S_un = m_vec + G * N;
  float* S_n = S_un + 262144;
  float* Bm = S_n + 262144;
  float* T1 = Bm + 262144;
  float* T2 = T1 + 262144;
  float* normacc = T2 + 262144;
  float* scaleg = normacc + G;

  hipMemsetAsync(normacc, 0, G * sizeof(float), stream);
  if (big) {
    k_syrk<32><<<dim3(32, G), 256, 0, stream>>>(Wt, partC, partRS);
    k_reduce<32><<<dim3(16, G), 256, 0, stream>>>(partC, partRS, m_vec, S_un, normacc);
  } else {
    k_syrk<16><<<dim3(16, G), 256, 0, stream>>>(Wt, partC, partRS);
    k_reduce<16><<<dim3(16, G), 256, 0, stream>>>(partC, partRS, m_vec, S_un, normacc);
  }
  k_nsinit<<<dim3(8, G), 256, 0, stream>>>(S_un, normacc, S_n, Bm, scaleg);
  for (int it = 0; it < 4; ++it) {
    k_nsmm2<<<dim3(8, 2, G), 256, 0, stream>>>(Bm, S_n, T1, T2);
    k_nsupd<<<dim3(8, G), 256, 0, stream>>>(T1, T2, Bm);
  }
  k_final<<<dim3(FI / 128, G), 256, 0, stream>>>(Wt, Bm, m_vec, scaleg, outp);
}